// Round 5
// baseline (537.271 us; speedup 1.0000x reference)
//
#include <hip/hip_runtime.h>

#define D_MODEL 512
#define DINNER  1024
#define DSTATE  64
#define DTRANK  32
#define BSZ     2
#define NLEN    2048
#define NROWS   (BSZ*NLEN)   // 4096
#define XDBL_W  (DTRANK + 2*DSTATE)  // 160

typedef __attribute__((ext_vector_type(8))) short  bf16x8;
typedef __attribute__((ext_vector_type(4))) float  f32x4;
typedef __attribute__((ext_vector_type(8))) unsigned short u16x8;

// ---------------- LayerNorm: one wave per row ----------------
__global__ __launch_bounds__(256) void ln_kernel(const float* __restrict__ x,
        const float* __restrict__ w, const float* __restrict__ bvec,
        float* __restrict__ xn) {
    const int wid = threadIdx.x >> 6, lane = threadIdx.x & 63;
    const int row = (blockIdx.x << 2) + wid;
    const float4* xp = (const float4*)(x + (size_t)row * D_MODEL);
    float4 v0 = xp[lane], v1 = xp[lane + 64];
    float s = v0.x + v0.y + v0.z + v0.w + v1.x + v1.y + v1.z + v1.w;
    float q = v0.x*v0.x + v0.y*v0.y + v0.z*v0.z + v0.w*v0.w
            + v1.x*v1.x + v1.y*v1.y + v1.z*v1.z + v1.w*v1.w;
    #pragma unroll
    for (int m = 32; m; m >>= 1) { s += __shfl_xor(s, m); q += __shfl_xor(q, m); }
    const float mean = s * (1.f / D_MODEL);
    const float var  = q * (1.f / D_MODEL) - mean * mean;
    const float rstd = rsqrtf(var + 1e-5f);
    const float4* wp = (const float4*)w;
    const float4* bp = (const float4*)bvec;
    float4 w0 = wp[lane], w1 = wp[lane + 64], b0 = bp[lane], b1 = bp[lane + 64];
    float4 o0, o1;
    o0.x = (v0.x - mean) * rstd * w0.x + b0.x;
    o0.y = (v0.y - mean) * rstd * w0.y + b0.y;
    o0.z = (v0.z - mean) * rstd * w0.z + b0.z;
    o0.w = (v0.w - mean) * rstd * w0.w + b0.w;
    o1.x = (v1.x - mean) * rstd * w1.x + b1.x;
    o1.y = (v1.y - mean) * rstd * w1.y + b1.y;
    o1.z = (v1.z - mean) * rstd * w1.z + b1.z;
    o1.w = (v1.w - mean) * rstd * w1.w + b1.w;
    float4* op = (float4*)(xn + (size_t)row * D_MODEL);
    op[lane] = o0; op[lane + 64] = o1;
}

// ---- pack fp32 (R x K row-major) -> fragment-major split-bf16 [2*K/32][Rpad/16][64][8]
// frag element j of lane l = src[rt*16 + (l&15)][kt*32 + 8*(l>>4) + j]
// hi region: ktiles [0, K/32), lo region: ktiles [K/32, 2*K/32). rows >= R -> 0.
__global__ __launch_bounds__(256) void pack_hilo(const float* __restrict__ src,
        unsigned short* __restrict__ dst, int R, int RT /* Rpad/16 */, int K) {
    const int wid = threadIdx.x >> 6, lane = threadIdx.x & 63;
    const int gid = blockIdx.x * 4 + wid;          // in [0, (K/32)*RT)
    const int kt = gid / RT, rt = gid - kt * RT;
    const int row = (rt << 4) + (lane & 15);
    const int KTK = K >> 5;
    u16x8 hi = {}, lo = {};
    if (row < R) {
        const float* s = src + (size_t)row * K + kt * 32 + ((lane >> 4) << 3);
        float4 f0 = *(const float4*)s;
        float4 f1 = *(const float4*)(s + 4);
        float ff[8] = {f0.x,f0.y,f0.z,f0.w,f1.x,f1.y,f1.z,f1.w};
        #pragma unroll
        for (int j = 0; j < 8; ++j) {
            unsigned int u  = __float_as_uint(ff[j]);
            unsigned int hb = (u + 0x7fffu + ((u >> 16) & 1)) >> 16;     // RNE bf16
            float rem = ff[j] - __uint_as_float(hb << 16);
            unsigned int ul = __float_as_uint(rem);
            unsigned int lb = (ul + 0x7fffu + ((ul >> 16) & 1)) >> 16;
            hi[j] = (unsigned short)hb;
            lo[j] = (unsigned short)lb;
        }
    }
    *(u16x8*)(dst + ((size_t)kt * RT + rt) * 512 + lane * 8) = hi;
    *(u16x8*)(dst + ((size_t)(kt + KTK) * RT + rt) * 512 + lane * 8) = lo;
}

// ---- MFMA GEMM on packed operands: C(M,N) = A(M,K)*B(N,K)^T, fp32-accurate via
// 3-term split: virtual kt in [0,3*K/32) -> A tile (hi,lo,hi), B tile (hi,hi,lo).
// Pack layout is fragment-major so staging is linear and LDS reads lane-linear.
template<int BM, int BN, int WR, int WC>
__global__ __launch_bounds__(256) void gemm_mfma(
        const unsigned short* __restrict__ Ap, const unsigned short* __restrict__ Bp,
        int M, int N, int K,
        float* __restrict__ out0, float* __restrict__ out1, int split) {
    constexpr int MI = BM / (WR * 16);
    constexpr int NI = BN / (WC * 16);
    constexpr int APASS = (BM * 64) / 4096;   // staging passes (256 thr x 16B)
    constexpr int BPASS = (BN * 64) / 4096;
    __shared__ __align__(16) unsigned short sA[BM * 32];
    __shared__ __align__(16) unsigned short sB[BN * 32];
    const int tid = threadIdx.x;
    const int wid = tid >> 6, lane = tid & 63;
    const int wr = wid / WC, wc = wid % WC;
    const int m0 = blockIdx.y * BM, n0 = blockIdx.x * BN;
    const int MT = M >> 4, NT = N >> 4;
    const int KTK = K >> 5;
    const int KTv = 3 * KTK;
    f32x4 acc[MI][NI] = {};
    int4 ra[APASS], rb[BPASS];
    // prologue: load tile kt=0
    {
        const char* gA = (const char*)Ap + ((size_t)0 * MT + (m0 >> 4)) * 1024;
        const char* gB = (const char*)Bp + ((size_t)0 * NT + (n0 >> 4)) * 1024;
        #pragma unroll
        for (int p = 0; p < APASS; ++p) ra[p] = *(const int4*)(gA + p*4096 + tid*16);
        #pragma unroll
        for (int p = 0; p < BPASS; ++p) rb[p] = *(const int4*)(gB + p*4096 + tid*16);
    }
    for (int kt = 0; kt < KTv; ++kt) {
        __syncthreads();   // previous tile's readers done
        #pragma unroll
        for (int p = 0; p < APASS; ++p) *(int4*)((char*)sA + p*4096 + tid*16) = ra[p];
        #pragma unroll
        for (int p = 0; p < BPASS; ++p) *(int4*)((char*)sB + p*4096 + tid*16) = rb[p];
        if (kt + 1 < KTv) {   // prefetch next tile into regs (overlaps MFMA below)
            const int k1 = kt + 1;
            const int a_kt = (k1 < 2 * KTK) ? k1 : k1 - 2 * KTK;   // hi,lo,hi
            const int b_kt = (k1 < KTK) ? k1 : k1 - KTK;           // hi,hi,lo
            const char* gA = (const char*)Ap + ((size_t)a_kt * MT + (m0 >> 4)) * 1024;
            const char* gB = (const char*)Bp + ((size_t)b_kt * NT + (n0 >> 4)) * 1024;
            #pragma unroll
            for (int p = 0; p < APASS; ++p) ra[p] = *(const int4*)(gA + p*4096 + tid*16);
            #pragma unroll
            for (int p = 0; p < BPASS; ++p) rb[p] = *(const int4*)(gB + p*4096 + tid*16);
        }
        __syncthreads();   // LDS tile ready
        bf16x8 af[MI], bf[NI];
        #pragma unroll
        for (int mi = 0; mi < MI; ++mi)
            af[mi] = *(const bf16x8*)((const char*)sA + (wr*MI + mi)*1024 + lane*16);
        #pragma unroll
        for (int ni = 0; ni < NI; ++ni)
            bf[ni] = *(const bf16x8*)((const char*)sB + (wc*NI + ni)*1024 + lane*16);
        #pragma unroll
        for (int mi = 0; mi < MI; ++mi)
            #pragma unroll
            for (int ni = 0; ni < NI; ++ni)
                acc[mi][ni] = __builtin_amdgcn_mfma_f32_16x16x32_bf16(
                    af[mi], bf[ni], acc[mi][ni], 0, 0, 0);
    }
    // epilogue: C/D layout col=lane&15, row=(lane>>4)*4+reg (m89-verified)
    #pragma unroll
    for (int mi = 0; mi < MI; ++mi) {
        #pragma unroll
        for (int ni = 0; ni < NI; ++ni) {
            const int col = n0 + (wc*NI + ni)*16 + (lane & 15);
            const int rb_ = m0 + (wr*MI + mi)*16 + ((lane >> 4) << 2);
            if (col < split) {
                #pragma unroll
                for (int r = 0; r < 4; ++r)
                    out0[(size_t)(rb_ + r) * split + col] = acc[mi][ni][r];
            } else if (out1 != nullptr) {
                #pragma unroll
                for (int r = 0; r < 4; ++r)
                    out1[(size_t)(rb_ + r) * (N - split) + (col - split)] = acc[mi][ni][r];
            }
        }
    }
}

// ---------------- causal depthwise conv (k=4) + SiLU ----------------
__global__ __launch_bounds__(256) void conv_kernel(const float* __restrict__ xr,
        const float* __restrict__ cw, const float* __restrict__ cb,
        float* __restrict__ xi) {
    const int g = blockIdx.x * 256 + threadIdx.x;
    const int d = g & (DINNER - 1);
    const int n = (g >> 10) & (NLEN - 1);
    const float4 wv = *(const float4*)(cw + d * 4);
    const float* p = xr + g;
    float acc = cb[d];
    acc = fmaf(wv.w, p[0], acc);
    if (n >= 1) acc = fmaf(wv.z, p[-DINNER], acc);
    if (n >= 2) acc = fmaf(wv.y, p[-2 * DINNER], acc);
    if (n >= 3) acc = fmaf(wv.x, p[-3 * DINNER], acc);
    xi[g] = acc / (1.f + expf(-acc));
}

// ---------------- dt = softplus(dtr @ W^T + b) ----------------
__global__ __launch_bounds__(256) void dt_kernel(const float* __restrict__ xdbl,
        const float* __restrict__ W, const float* __restrict__ bias,
        float* __restrict__ dt) {
    const int row = blockIdx.x;
    __shared__ float r[DTRANK];
    if (threadIdx.x < DTRANK) r[threadIdx.x] = xdbl[(size_t)row * XDBL_W + threadIdx.x];
    __syncthreads();
    #pragma unroll
    for (int q = 0; q < 4; ++q) {
        const int d = (q << 8) + threadIdx.x;
        float acc = bias[d];
        const float* wp = W + (size_t)d * DTRANK;
        #pragma unroll
        for (int j = 0; j < DTRANK; ++j) acc = fmaf(r[j], wp[j], acc);
        dt[(size_t)row * DINNER + d] = (acc > 20.f) ? acc : log1pf(expf(acc));
    }
}

// ---------------- selective scan (round-4 structure, unchanged) ----------------
__global__ __launch_bounds__(256) void scan_kernel(const float* __restrict__ dt,
        const float* __restrict__ u, const float* __restrict__ xdbl,
        const float* __restrict__ A_log, float* __restrict__ yt) {
    __shared__ float p[4][32][65];
    const int wid = threadIdx.x >> 6;
    const int w = (blockIdx.x << 2) + wid;
    const int lane = threadIdx.x & 63;
    const int b = w >> 10, d = w & (DINNER - 1);
    const float* dtp = dt + (size_t)b * NLEN * DINNER + d;
    const float* up  = u  + (size_t)b * NLEN * DINNER + d;
    const float* Bb  = xdbl + (size_t)b * NLEN * XDBL_W + DTRANK + lane;
    float* yp = yt + ((size_t)b * DINNER + d) * NLEN;
    const float kA = -__builtin_amdgcn_exp2f(A_log[d * DSTATE + lane] * 1.44269504f)
                     * 1.44269504f;
    float (*pw)[65] = p[wid];
    const int rn = lane & 31;
    const int rs = (lane >> 5) << 5;
    float h = 0.f;
    for (int n0 = 0; n0 < NLEN; n0 += 64) {
        const float dtv = dtp[(size_t)(n0 + lane) * DINNER];
        const float uv  = up [(size_t)(n0 + lane) * DINNER];
        const float dtu = dtv * uv;
        #pragma unroll
        for (int half = 0; half < 2; ++half) {
            const float* Bn = Bb + (size_t)(n0 + 32 * half) * XDBL_W;
            #pragma unroll
            for (int j = 0; j < 32; ++j) {
                const float Bv = Bn[j * XDBL_W];
                const float Cv = Bn[j * XDBL_W + DSTATE];
                const float sdt = __int_as_float(
                    __builtin_amdgcn_readlane(__float_as_int(dtv), 32 * half + j));
                const float sdu = __int_as_float(
                    __builtin_amdgcn_readlane(__float_as_int(dtu), 32 * half + j));
                const float dA = __builtin_amdgcn_exp2f(kA * sdt);
                h = fmaf(dA, h, sdu * Bv);
                pw[j][lane] = h * Cv;
            }
            float y0 = 0.f, y1 = 0.f, y2 = 0.f, y3 = 0.f;
            #pragma unroll
            for (int i = 0; i < 32; i += 4) {
                y0 += pw[rn][rs + i];
                y1 += pw[rn][rs + i + 1];
                y2 += pw[rn][rs + i + 2];
                y3 += pw[rn][rs + i + 3];
            }
            float y = (y0 + y1) + (y2 + y3);
            y += __shfl_xor(y, 32);
            if (lane < 32) yp[n0 + 32 * half + rn] = y;
        }
    }
}

// ---------------- gate: yg = (yt^T + xi*D) * silu(z) ----------------
__global__ __launch_bounds__(256) void gate_kernel(const float* __restrict__ yt,
        const float* __restrict__ xi, const float* __restrict__ z,
        const float* __restrict__ Dv, float* __restrict__ yg) {
    const int g = blockIdx.x * 256 + threadIdx.x;
    const int d = g & (DINNER - 1);
    const int n = (g >> 10) & (NLEN - 1);
    const int b = g >> 21;
    const float yv = yt[((size_t)b * DINNER + d) * NLEN + n];
    const float zv = z[g];
    yg[g] = fmaf(xi[g], Dv[d], yv) * (zv / (1.f + expf(-zv)));
}

extern "C" void kernel_launch(void* const* d_in, const int* in_sizes, int n_in,
                              void* d_out, int out_size, void* d_ws, size_t ws_size,
                              hipStream_t stream) {
    const float* x         = (const float*)d_in[0];
    const float* norm_w    = (const float*)d_in[1];
    const float* norm_b    = (const float*)d_in[2];
    const float* in_proj_w = (const float*)d_in[3];
    const float* conv_w    = (const float*)d_in[4];
    const float* conv_b    = (const float*)d_in[5];
    const float* x_proj_w  = (const float*)d_in[6];
    const float* dt_proj_w = (const float*)d_in[7];
    const float* dt_proj_b = (const float*)d_in[8];
    const float* A_log     = (const float*)d_in[9];
    const float* Dvec      = (const float*)d_in[10];
    const float* out_proj_w= (const float*)d_in[11];
    float* out = (float*)d_out;
    float* ws  = (float*)d_ws;

    const size_t M1 = (size_t)1024 * 1024;
    float* xn_dt = ws;                  // xn (2M f) then dt (4M f)
    float* xiraw = ws + 4*M1;           // xi pre-conv; later yg
    float* zbuf  = ws + 8*M1;
    float* xibuf = ws + 12*M1;
    float* xdbl  = ws + 16*M1;          // 0.66M f
    float* ytbuf = ws + 17*M1;          // 4M f
    unsigned short* Apack = (unsigned short*)(ws + 21*M1);  // 8.39M ushorts
    unsigned short* Bpack = (unsigned short*)(ws + 25*M1);  // 2.1M ushorts
    // total 26M floats = 104 MB

    ln_kernel<<<NROWS / 4, 256, 0, stream>>>(x, norm_w, norm_b, xn_dt);

    // ---- in_proj: M=4096,N=2048,K=512 ----
    pack_hilo<<<(16 * 256) / 4, 256, 0, stream>>>(xn_dt, Apack, 4096, 256, 512);
    pack_hilo<<<(16 * 128) / 4, 256, 0, stream>>>(in_proj_w, Bpack, 2048, 128, 512);
    gemm_mfma<128,128,2,2><<<dim3(16, 32), 256, 0, stream>>>(
        Apack, Bpack, 4096, 2048, 512, xiraw, zbuf, DINNER);

    conv_kernel<<<(BSZ * NLEN * DINNER) / 256, 256, 0, stream>>>(
        xiraw, conv_w, conv_b, xibuf);

    // ---- x_proj: M=4096,N=160(pad 256),K=1024 ----
    pack_hilo<<<(32 * 256) / 4, 256, 0, stream>>>(xibuf, Apack, 4096, 256, 1024);
    pack_hilo<<<(32 * 16) / 4, 256, 0, stream>>>(x_proj_w, Bpack, 160, 16, 1024);
    gemm_mfma<64,128,1,4><<<dim3(2, 64), 256, 0, stream>>>(
        Apack, Bpack, 4096, 256, 1024, xdbl, nullptr, XDBL_W);

    dt_kernel<<<NROWS, 256, 0, stream>>>(xdbl, dt_proj_w, dt_proj_b, xn_dt);
    scan_kernel<<<(BSZ * DINNER) / 4, 256, 0, stream>>>(
        xn_dt, xibuf, xdbl, A_log, ytbuf);
    gate_kernel<<<(BSZ * NLEN * DINNER) / 256, 256, 0, stream>>>(
        ytbuf, xibuf, zbuf, Dvec, xiraw);

    // ---- out_proj: M=4096,N=512,K=1024 ----
    pack_hilo<<<(32 * 256) / 4, 256, 0, stream>>>(xiraw, Apack, 4096, 256, 1024);
    pack_hilo<<<(32 * 32) / 4, 256, 0, stream>>>(out_proj_w, Bpack, 512, 32, 1024);
    gemm_mfma<64,128,1,4><<<dim3(4, 64), 256, 0, stream>>>(
        Apack, Bpack, 4096, 512, 1024, out, nullptr, D_MODEL);
}

// Round 6
// 423.263 us; speedup vs baseline: 1.2694x; 1.2694x over previous
//
#include <hip/hip_runtime.h>

#define D_MODEL 512
#define DINNER  1024
#define DSTATE  64
#define DTRANK  32
#define BSZ     2
#define NLEN    2048
#define NROWS   (BSZ*NLEN)   // 4096
#define XDBL_W  (DTRANK + 2*DSTATE)  // 160

typedef __attribute__((ext_vector_type(8))) short  bf16x8;
typedef __attribute__((ext_vector_type(4))) float  f32x4;
typedef __attribute__((ext_vector_type(8))) unsigned short u16x8;

// ---------------- LayerNorm: one wave per row ----------------
__global__ __launch_bounds__(256) void ln_kernel(const float* __restrict__ x,
        const float* __restrict__ w, const float* __restrict__ bvec,
        float* __restrict__ xn) {
    const int wid = threadIdx.x >> 6, lane = threadIdx.x & 63;
    const int row = (blockIdx.x << 2) + wid;
    const float4* xp = (const float4*)(x + (size_t)row * D_MODEL);
    float4 v0 = xp[lane], v1 = xp[lane + 64];
    float s = v0.x + v0.y + v0.z + v0.w + v1.x + v1.y + v1.z + v1.w;
    float q = v0.x*v0.x + v0.y*v0.y + v0.z*v0.z + v0.w*v0.w
            + v1.x*v1.x + v1.y*v1.y + v1.z*v1.z + v1.w*v1.w;
    #pragma unroll
    for (int m = 32; m; m >>= 1) { s += __shfl_xor(s, m); q += __shfl_xor(q, m); }
    const float mean = s * (1.f / D_MODEL);
    const float var  = q * (1.f / D_MODEL) - mean * mean;
    const float rstd = rsqrtf(var + 1e-5f);
    const float4* wp = (const float4*)w;
    const float4* bp = (const float4*)bvec;
    float4 w0 = wp[lane], w1 = wp[lane + 64], b0 = bp[lane], b1 = bp[lane + 64];
    float4 o0, o1;
    o0.x = (v0.x - mean) * rstd * w0.x + b0.x;
    o0.y = (v0.y - mean) * rstd * w0.y + b0.y;
    o0.z = (v0.z - mean) * rstd * w0.z + b0.z;
    o0.w = (v0.w - mean) * rstd * w0.w + b0.w;
    o1.x = (v1.x - mean) * rstd * w1.x + b1.x;
    o1.y = (v1.y - mean) * rstd * w1.y + b1.y;
    o1.z = (v1.z - mean) * rstd * w1.z + b1.z;
    o1.w = (v1.w - mean) * rstd * w1.w + b1.w;
    float4* op = (float4*)(xn + (size_t)row * D_MODEL);
    op[lane] = o0; op[lane + 64] = o1;
}

// ---- pack fp32 (R x K row-major) -> fragment-major split-bf16 [2*K/32][Rpad/16][64][8]
// frag element j of lane l = src[rt*16 + (l&15)][kt*32 + 8*(l>>4) + j]
// hi region: ktiles [0, K/32), lo region: ktiles [K/32, 2*K/32). rows >= R -> 0.
__global__ __launch_bounds__(256) void pack_hilo(const float* __restrict__ src,
        unsigned short* __restrict__ dst, int R, int RT /* Rpad/16 */, int K) {
    const int wid = threadIdx.x >> 6, lane = threadIdx.x & 63;
    const int gid = blockIdx.x * 4 + wid;          // in [0, (K/32)*RT)
    const int kt = gid / RT, rt = gid - kt * RT;
    const int row = (rt << 4) + (lane & 15);
    const int KTK = K >> 5;
    u16x8 hi = {}, lo = {};
    if (row < R) {
        const float* s = src + (size_t)row * K + kt * 32 + ((lane >> 4) << 3);
        float4 f0 = *(const float4*)s;
        float4 f1 = *(const float4*)(s + 4);
        float ff[8] = {f0.x,f0.y,f0.z,f0.w,f1.x,f1.y,f1.z,f1.w};
        #pragma unroll
        for (int j = 0; j < 8; ++j) {
            unsigned int u  = __float_as_uint(ff[j]);
            unsigned int hb = (u + 0x7fffu + ((u >> 16) & 1)) >> 16;     // RNE bf16
            float rem = ff[j] - __uint_as_float(hb << 16);
            unsigned int ul = __float_as_uint(rem);
            unsigned int lb = (ul + 0x7fffu + ((ul >> 16) & 1)) >> 16;
            hi[j] = (unsigned short)hb;
            lo[j] = (unsigned short)lb;
        }
    }
    *(u16x8*)(dst + ((size_t)kt * RT + rt) * 512 + lane * 8) = hi;
    *(u16x8*)(dst + ((size_t)(kt + KTK) * RT + rt) * 512 + lane * 8) = lo;
}

// ---- MFMA GEMM on packed operands: C(M,N) = A(M,K)*B(N,K)^T.
// Column blocks with n0 < cols3 use 3-term split (fp32-accurate): virtual kt in
// [0,3*K/32) -> A (hi,lo,hi), B (hi,hi,lo). Blocks with n0 >= cols3 use plain
// bf16 (1 term, hi*hi). Staging via global_load_lds width=16 (m97 structure):
// pack layout is fragment-major so LDS dest is linear (wave base + lane*16).
template<int BM, int BN, int WR, int WC>
__global__ __launch_bounds__(256) void gemm_mfma(
        const unsigned short* __restrict__ Ap, const unsigned short* __restrict__ Bp,
        int M, int N, int K, int cols3,
        float* __restrict__ out0, float* __restrict__ out1, int split) {
    constexpr int MI = BM / (WR * 16);
    constexpr int NI = BN / (WC * 16);
    constexpr int APASS = (BM * 64) / 4096;   // staging passes (256 thr x 16B)
    constexpr int BPASS = (BN * 64) / 4096;
    __shared__ __align__(16) unsigned short sA[BM * 32];
    __shared__ __align__(16) unsigned short sB[BN * 32];
    const int tid = threadIdx.x;
    const int wid = tid >> 6, lane = tid & 63;
    const int wr = wid / WC, wc = wid % WC;
    const int m0 = blockIdx.y * BM, n0 = blockIdx.x * BN;
    const int MT = M >> 4, NT = N >> 4;
    const int KTK = K >> 5;
    const int KTv = (n0 < cols3) ? 3 * KTK : KTK;
    f32x4 acc[MI][NI] = {};
    for (int kt = 0; kt < KTv; ++kt) {
        const int a_kt = (kt < 2 * KTK) ? kt : kt - 2 * KTK;   // hi, lo, hi
        const int b_kt = (kt < KTK) ? kt : kt - KTK;           // hi, hi, lo
        const char* gA = (const char*)(Ap + ((size_t)a_kt * MT + (m0 >> 4)) * 512);
        const char* gB = (const char*)(Bp + ((size_t)b_kt * NT + (n0 >> 4)) * 512);
        __syncthreads();   // previous tile's readers done
        #pragma unroll
        for (int p = 0; p < APASS; ++p)
            __builtin_amdgcn_global_load_lds(
                (const __attribute__((address_space(1))) void*)(gA + p * 4096 + tid * 16),
                (__attribute__((address_space(3))) void*)((char*)sA + p * 4096 + tid * 16),
                16, 0, 0);
        #pragma unroll
        for (int p = 0; p < BPASS; ++p)
            __builtin_amdgcn_global_load_lds(
                (const __attribute__((address_space(1))) void*)(gB + p * 4096 + tid * 16),
                (__attribute__((address_space(3))) void*)((char*)sB + p * 4096 + tid * 16),
                16, 0, 0);
        __syncthreads();   // vmcnt(0) drained by compiler before barrier -> tile ready
        bf16x8 af[MI], bfr[NI];
        #pragma unroll
        for (int mi = 0; mi < MI; ++mi)
            af[mi] = *(const bf16x8*)((const char*)sA + (wr*MI + mi)*1024 + lane*16);
        #pragma unroll
        for (int ni = 0; ni < NI; ++ni)
            bfr[ni] = *(const bf16x8*)((const char*)sB + (wc*NI + ni)*1024 + lane*16);
        #pragma unroll
        for (int mi = 0; mi < MI; ++mi)
            #pragma unroll
            for (int ni = 0; ni < NI; ++ni)
                acc[mi][ni] = __builtin_amdgcn_mfma_f32_16x16x32_bf16(
                    af[mi], bfr[ni], acc[mi][ni], 0, 0, 0);
    }
    // epilogue: C/D layout col=lane&15, row=(lane>>4)*4+reg (m89-verified)
    #pragma unroll
    for (int mi = 0; mi < MI; ++mi) {
        #pragma unroll
        for (int ni = 0; ni < NI; ++ni) {
            const int col = n0 + (wc*NI + ni)*16 + (lane & 15);
            const int rb_ = m0 + (wr*MI + mi)*16 + ((lane >> 4) << 2);
            if (col < split) {
                #pragma unroll
                for (int r = 0; r < 4; ++r)
                    out0[(size_t)(rb_ + r) * split + col] = acc[mi][ni][r];
            } else if (out1 != nullptr) {
                #pragma unroll
                for (int r = 0; r < 4; ++r)
                    out1[(size_t)(rb_ + r) * (N - split) + (col - split)] = acc[mi][ni][r];
            }
        }
    }
}

// ---------------- causal depthwise conv (k=4) + SiLU ----------------
__global__ __launch_bounds__(256) void conv_kernel(const float* __restrict__ xr,
        const float* __restrict__ cw, const float* __restrict__ cb,
        float* __restrict__ xi) {
    const int g = blockIdx.x * 256 + threadIdx.x;
    const int d = g & (DINNER - 1);
    const int n = (g >> 10) & (NLEN - 1);
    const float4 wv = *(const float4*)(cw + d * 4);
    const float* p = xr + g;
    float acc = cb[d];
    acc = fmaf(wv.w, p[0], acc);
    if (n >= 1) acc = fmaf(wv.z, p[-DINNER], acc);
    if (n >= 2) acc = fmaf(wv.y, p[-2 * DINNER], acc);
    if (n >= 3) acc = fmaf(wv.x, p[-3 * DINNER], acc);
    xi[g] = acc / (1.f + expf(-acc));
}

// ---------------- dt = softplus(dtr @ W^T + b) ----------------
__global__ __launch_bounds__(256) void dt_kernel(const float* __restrict__ xdbl,
        const float* __restrict__ W, const float* __restrict__ bias,
        float* __restrict__ dt) {
    const int row = blockIdx.x;
    __shared__ float r[DTRANK];
    if (threadIdx.x < DTRANK) r[threadIdx.x] = xdbl[(size_t)row * XDBL_W + threadIdx.x];
    __syncthreads();
    #pragma unroll
    for (int q = 0; q < 4; ++q) {
        const int d = (q << 8) + threadIdx.x;
        float acc = bias[d];
        const float* wp = W + (size_t)d * DTRANK;
        #pragma unroll
        for (int j = 0; j < DTRANK; ++j) acc = fmaf(r[j], wp[j], acc);
        dt[(size_t)row * DINNER + d] = (acc > 20.f) ? acc : log1pf(expf(acc));
    }
}

// ---------------- selective scan (round-4 structure, unchanged) ----------------
__global__ __launch_bounds__(256) void scan_kernel(const float* __restrict__ dt,
        const float* __restrict__ u, const float* __restrict__ xdbl,
        const float* __restrict__ A_log, float* __restrict__ yt) {
    __shared__ float p[4][32][65];
    const int wid = threadIdx.x >> 6;
    const int w = (blockIdx.x << 2) + wid;
    const int lane = threadIdx.x & 63;
    const int b = w >> 10, d = w & (DINNER - 1);
    const float* dtp = dt + (size_t)b * NLEN * DINNER + d;
    const float* up  = u  + (size_t)b * NLEN * DINNER + d;
    const float* Bb  = xdbl + (size_t)b * NLEN * XDBL_W + DTRANK + lane;
    float* yp = yt + ((size_t)b * DINNER + d) * NLEN;
    const float kA = -__builtin_amdgcn_exp2f(A_log[d * DSTATE + lane] * 1.44269504f)
                     * 1.44269504f;
    float (*pw)[65] = p[wid];
    const int rn = lane & 31;
    const int rs = (lane >> 5) << 5;
    float h = 0.f;
    for (int n0 = 0; n0 < NLEN; n0 += 64) {
        const float dtv = dtp[(size_t)(n0 + lane) * DINNER];
        const float uv  = up [(size_t)(n0 + lane) * DINNER];
        const float dtu = dtv * uv;
        #pragma unroll
        for (int half = 0; half < 2; ++half) {
            const float* Bn = Bb + (size_t)(n0 + 32 * half) * XDBL_W;
            #pragma unroll
            for (int j = 0; j < 32; ++j) {
                const float Bv = Bn[j * XDBL_W];
                const float Cv = Bn[j * XDBL_W + DSTATE];
                const float sdt = __int_as_float(
                    __builtin_amdgcn_readlane(__float_as_int(dtv), 32 * half + j));
                const float sdu = __int_as_float(
                    __builtin_amdgcn_readlane(__float_as_int(dtu), 32 * half + j));
                const float dA = __builtin_amdgcn_exp2f(kA * sdt);
                h = fmaf(dA, h, sdu * Bv);
                pw[j][lane] = h * Cv;
            }
            float y0 = 0.f, y1 = 0.f, y2 = 0.f, y3 = 0.f;
            #pragma unroll
            for (int i = 0; i < 32; i += 4) {
                y0 += pw[rn][rs + i];
                y1 += pw[rn][rs + i + 1];
                y2 += pw[rn][rs + i + 2];
                y3 += pw[rn][rs + i + 3];
            }
            float y = (y0 + y1) + (y2 + y3);
            y += __shfl_xor(y, 32);
            if (lane < 32) yp[n0 + 32 * half + rn] = y;
        }
    }
}

// ---------------- gate: yg = (yt^T + xi*D) * silu(z) ----------------
__global__ __launch_bounds__(256) void gate_kernel(const float* __restrict__ yt,
        const float* __restrict__ xi, const float* __restrict__ z,
        const float* __restrict__ Dv, float* __restrict__ yg) {
    const int g = blockIdx.x * 256 + threadIdx.x;
    const int d = g & (DINNER - 1);
    const int n = (g >> 10) & (NLEN - 1);
    const int b = g >> 21;
    const float yv = yt[((size_t)b * DINNER + d) * NLEN + n];
    const float zv = z[g];
    yg[g] = fmaf(xi[g], Dv[d], yv) * (zv / (1.f + expf(-zv)));
}

extern "C" void kernel_launch(void* const* d_in, const int* in_sizes, int n_in,
                              void* d_out, int out_size, void* d_ws, size_t ws_size,
                              hipStream_t stream) {
    const float* x         = (const float*)d_in[0];
    const float* norm_w    = (const float*)d_in[1];
    const float* norm_b    = (const float*)d_in[2];
    const float* in_proj_w = (const float*)d_in[3];
    const float* conv_w    = (const float*)d_in[4];
    const float* conv_b    = (const float*)d_in[5];
    const float* x_proj_w  = (const float*)d_in[6];
    const float* dt_proj_w = (const float*)d_in[7];
    const float* dt_proj_b = (const float*)d_in[8];
    const float* A_log     = (const float*)d_in[9];
    const float* Dvec      = (const float*)d_in[10];
    const float* out_proj_w= (const float*)d_in[11];
    float* out = (float*)d_out;
    float* ws  = (float*)d_ws;

    const size_t M1 = (size_t)1024 * 1024;
    float* xn_dt = ws;                  // xn (2M f) then dt (4M f)
    float* xiraw = ws + 4*M1;           // xi pre-conv; later yg
    float* zbuf  = ws + 8*M1;
    float* xibuf = ws + 12*M1;
    float* xdbl  = ws + 16*M1;          // 0.66M f
    float* ytbuf = ws + 17*M1;          // 4M f
    unsigned short* Apack = (unsigned short*)(ws + 21*M1);  // up to 16.8M ushorts
    unsigned short* Bpack = (unsigned short*)(ws + 26*M1);  // up to 4.2M ushorts
    // total ~28M floats = 112 MB

    ln_kernel<<<NROWS / 4, 256, 0, stream>>>(x, norm_w, norm_b, xn_dt);

    // ---- in_proj: M=4096,N=2048,K=512; xi half 3-term, z half 1-term ----
    pack_hilo<<<(16 * 256) / 4, 256, 0, stream>>>(xn_dt, Apack, 4096, 256, 512);
    pack_hilo<<<(16 * 128) / 4, 256, 0, stream>>>(in_proj_w, Bpack, 2048, 128, 512);
    gemm_mfma<128,128,2,2><<<dim3(16, 32), 256, 0, stream>>>(
        Apack, Bpack, 4096, 2048, 512, /*cols3=*/DINNER, xiraw, zbuf, DINNER);

    conv_kernel<<<(BSZ * NLEN * DINNER) / 256, 256, 0, stream>>>(
        xiraw, conv_w, conv_b, xibuf);

    // ---- x_proj: M=4096,N=160(pad 256, cover 192),K=1024; 3-term ----
    pack_hilo<<<(32 * 256) / 4, 256, 0, stream>>>(xibuf, Apack, 4096, 256, 1024);
    pack_hilo<<<(32 * 16) / 4, 256, 0, stream>>>(x_proj_w, Bpack, 160, 16, 1024);
    gemm_mfma<64,64,2,2><<<dim3(3, 64), 256, 0, stream>>>(
        Apack, Bpack, 4096, 256, 1024, /*cols3=*/256, xdbl, nullptr, XDBL_W);

    dt_kernel<<<NROWS, 256, 0, stream>>>(xdbl, dt_proj_w, dt_proj_b, xn_dt);
    scan_kernel<<<(BSZ * DINNER) / 4, 256, 0, stream>>>(
        xn_dt, xibuf, xdbl, A_log, ytbuf);
    gate_kernel<<<(BSZ * NLEN * DINNER) / 256, 256, 0, stream>>>(
        ytbuf, xibuf, zbuf, Dvec, xiraw);

    // ---- out_proj: M=4096,N=512,K=1024; 3-term ----
    pack_hilo<<<(32 * 256) / 4, 256, 0, stream>>>(xiraw, Apack, 4096, 256, 1024);
    pack_hilo<<<(32 * 32) / 4, 256, 0, stream>>>(out_proj_w, Bpack, 512, 32, 1024);
    gemm_mfma<64,64,2,2><<<dim3(8, 64), 256, 0, stream>>>(
        Apack, Bpack, 4096, 512, 1024, /*cols3=*/512, out, nullptr, D_MODEL);
}